// Round 1
// baseline (106.074 us; speedup 1.0000x reference)
//
#include <hip/hip_runtime.h>
#include <hip/hip_bf16.h>
#include <stdint.h>

#define NN 50000
#define DD 128
#define PP 6
#define LL 6
#define NPG 4          // nodes per 32-lane group in gather kernel
#define PAD 132        // padded LDS row (128 + 4) -> conflict-free strided reads

typedef float f4 __attribute__((ext_vector_type(4)));

__device__ __forceinline__ uint16_t f2bf(float f) {
  uint32_t u = __float_as_uint(f);
  u = (u + 0x7fffu + ((u >> 16) & 1u)) >> 16;   // round-to-nearest-even
  return (uint16_t)u;
}

// ---- kernel 0: feats f32 -> bf16 (halves gather traffic) ----
__global__ __launch_bounds__(256) void k_cvt(const float* __restrict__ in,
                                             uint16_t* __restrict__ out, int n4) {
  int i = blockIdx.x * 256 + threadIdx.x;
  if (i >= n4) return;
  f4 v = ((const f4*)in)[i];
  ushort4 o;
  o.x = f2bf(v.x); o.y = f2bf(v.y); o.z = f2bf(v.z); o.w = f2bf(v.w);
  ((ushort4*)out)[i] = o;
}

// ---- kernel 1: gather-weighted accumulate: acc[n,:] = (1/6) sum_{p,l} w[l,:]*feats_bf16[paths[p,n,l],:]
// 32 lanes cooperate on one node row (each lane owns 4 consecutive d).
__global__ __launch_bounds__(256) void k_gather(
    const uint16_t* __restrict__ fb,     // (NN, DD) bf16
    const int* __restrict__ paths,       // (PP, NN, LL) int32
    const float* __restrict__ w,         // (LL, DD) f32  (= path_weight1[0])
    float* __restrict__ acc) {           // (NN, DD) f32
  const int lane = threadIdx.x & 31;
  const int grp  = threadIdx.x >> 5;     // 0..7
  const int d0   = lane * 4;
  const int nbase = blockIdx.x * (8 * NPG) + grp * NPG;

  f4 wl[LL];
  #pragma unroll
  for (int l = 0; l < LL; ++l)
    wl[l] = *(const f4*)(w + l * DD + d0);

  #pragma unroll
  for (int ni = 0; ni < NPG; ++ni) {
    const int n = nbase + ni;
    if (n >= NN) return;                 // uniform within the 32-lane group
    f4 a = {0.f, 0.f, 0.f, 0.f};
    #pragma unroll
    for (int p = 0; p < PP; ++p) {
      #pragma unroll
      for (int l = 0; l < LL; ++l) {
        const int idx = paths[(p * NN + n) * LL + l];
        const uint2 v = *(const uint2*)(fb + idx * DD + d0);   // 4 bf16
        const float f0 = __uint_as_float(v.x << 16);
        const float f1 = __uint_as_float(v.x & 0xffff0000u);
        const float f2 = __uint_as_float(v.y << 16);
        const float f3 = __uint_as_float(v.y & 0xffff0000u);
        a.x = fmaf(wl[l].x, f0, a.x);
        a.y = fmaf(wl[l].y, f1, a.y);
        a.z = fmaf(wl[l].z, f2, a.z);
        a.w = fmaf(wl[l].w, f3, a.w);
      }
    }
    const float s = 1.f / 6.f;
    a.x *= s; a.y *= s; a.z *= s; a.w *= s;
    *(f4*)(acc + (size_t)n * DD + d0) = a;
  }
}

// ---- kernel 2: out = relu(acc @ W^T), W (128,128) row-major (o,d) ----
// 64-node tile per block; W staged in two 64-row LDS panels; 4n x 4o register tile.
__global__ __launch_bounds__(256) void k_fc(
    const float* __restrict__ acc,
    const float* __restrict__ fcw,
    float* __restrict__ out) {
  __shared__ float sA[64 * PAD];
  __shared__ float sW[64 * PAD];
  const int t = threadIdx.x;
  const int nb = blockIdx.x * 64;

  #pragma unroll
  for (int it = 0; it < 8; ++it) {
    const int i = it * 1024 + t * 4;
    const int r = i >> 7, c = i & 127;
    f4 v = {0.f, 0.f, 0.f, 0.f};
    if (nb + r < NN) v = *(const f4*)(acc + (size_t)(nb + r) * DD + c);
    *(f4*)(sA + r * PAD + c) = v;
  }

  const int tx = t & 15, ty = t >> 4;

  #pragma unroll
  for (int ob = 0; ob < 2; ++ob) {
    __syncthreads();                      // protect sW reuse across ob
    #pragma unroll
    for (int it = 0; it < 8; ++it) {
      const int i = it * 1024 + t * 4;
      const int r = i >> 7, c = i & 127;
      *(f4*)(sW + r * PAD + c) = *(const f4*)(fcw + (size_t)(ob * 64 + r) * DD + c);
    }
    __syncthreads();

    float ao[4][4];
    #pragma unroll
    for (int i = 0; i < 4; ++i)
      #pragma unroll
      for (int j = 0; j < 4; ++j) ao[i][j] = 0.f;

    for (int dd0 = 0; dd0 < DD; dd0 += 4) {
      f4 an[4], wo[4];
      #pragma unroll
      for (int i = 0; i < 4; ++i) an[i] = *(const f4*)(sA + (ty * 4 + i) * PAD + dd0);
      #pragma unroll
      for (int j = 0; j < 4; ++j) wo[j] = *(const f4*)(sW + (tx + 16 * j) * PAD + dd0);
      #pragma unroll
      for (int i = 0; i < 4; ++i)
        #pragma unroll
        for (int j = 0; j < 4; ++j) {
          ao[i][j] = fmaf(an[i].x, wo[j].x, ao[i][j]);
          ao[i][j] = fmaf(an[i].y, wo[j].y, ao[i][j]);
          ao[i][j] = fmaf(an[i].z, wo[j].z, ao[i][j]);
          ao[i][j] = fmaf(an[i].w, wo[j].w, ao[i][j]);
        }
    }

    #pragma unroll
    for (int i = 0; i < 4; ++i) {
      const int n = nb + ty * 4 + i;
      if (n >= NN) continue;
      #pragma unroll
      for (int j = 0; j < 4; ++j) {
        const int o = ob * 64 + tx + 16 * j;
        out[(size_t)n * DD + o] = fmaxf(ao[i][j], 0.f);
      }
    }
  }
}

extern "C" void kernel_launch(void* const* d_in, const int* in_sizes, int n_in,
                              void* d_out, int out_size, void* d_ws, size_t ws_size,
                              hipStream_t stream) {
  const float* feats = (const float*)d_in[0];
  const int*   paths = (const int*)d_in[1];       // int32 (jax x64 disabled)
  const float* pw1   = (const float*)d_in[4];     // (1,6,128) -> flat (6,128)
  const float* fcw   = (const float*)d_in[6];     // (128,128)
  float* out = (float*)d_out;

  uint16_t* fb  = (uint16_t*)d_ws;                                  // 12.8 MB
  float*    acc = (float*)((char*)d_ws + (size_t)NN * DD * 2);      // 25.6 MB

  const int n4 = NN * DD / 4;
  k_cvt<<<(n4 + 255) / 256, 256, 0, stream>>>(feats, fb, n4);
  k_gather<<<(NN + 8 * NPG - 1) / (8 * NPG), 256, 0, stream>>>(fb, paths, pw1, acc);
  k_fc<<<(NN + 63) / 64, 256, 0, stream>>>(acc, fcw, out);
}